// Round 1
// baseline (253.461 us; speedup 1.0000x reference)
//
#include <hip/hip_runtime.h>
#include <hip/hip_bf16.h>

// Round 8: occupancy push. r7 (=249us) was latency-bound at 31% occupancy:
// LDS 44032B -> 3 blocks/CU, plus a full-LDS zeroing pass (2752 uint4 stores,
// 8-way bank-conflicted) + extra barrier per block. This round:
//  - Phase 0 (LDS zeroing) removed: every consumed LDS word is written before
//    read; MFMA garbage in padding A-rows stays row-local and those output
//    rows are never stored/read. Padding-row READS over-read into adjacent
//    buffers by design (within smem).
//  - LDS shrunk 44032 -> 29568 B (24-row q/k/v/o/tmp; tmp overlays dead h)
//    -> 5 blocks/CU. Guarded c1 stores (row<24) also delete dead stores.
//  - attention scale hoisted into q registers.

typedef unsigned short u16;
typedef unsigned int u32;
typedef __attribute__((ext_vector_type(8))) short bf16x8;
typedef __attribute__((ext_vector_type(4))) float f32x4;

#define B_ 32
#define T_ 24
#define N_ 325
#define D_ 64

#define WQKV_OFF 0        // 3072 frags * 8 el = 24576 el
#define WO1_OFF  24576    // 512 frags  * 8 el = 4096 el
#define WO2_OFF  28672    // 512 frags  * 8 el = 4096 el
#define WS_ELS   32768

__device__ __align__(64) u16 g_ws[WS_ELS];

__device__ __forceinline__ u16 f2bf(float f) {
    u32 u = __float_as_uint(f);
    return (u16)((u + 0x7FFFu + ((u >> 16) & 1u)) >> 16);  // RNE
}
__device__ __forceinline__ u32 pack2(float a, float b) {
    return (u32)f2bf(a) | ((u32)f2bf(b) << 16);
}

// B-frag (16x16x32): lane l holds B[k = ks*32 + (l>>4)*8 + j][n = nt*16 + (l&15)]
__global__ void ta_repack(const float* __restrict__ Wq, const float* __restrict__ Wk,
                          const float* __restrict__ Wv, const float* __restrict__ Wo1,
                          const float* __restrict__ Wo2) {
    int f = blockIdx.x * 256 + threadIdx.x;   // 0..4095
    const float* src;
    u16* dst;
    if (f < 3072) {
        int nt = f >> 8, ks = (f >> 6) & 3, l = f & 63;
        int nn = nt * 16 + (l & 15);
        int kb = ks * 32 + ((l >> 4) & 3) * 8;
        const float* W = (nn < 64) ? Wq : (nn < 128 ? Wk : Wv);
        src = W + kb * 64 + (nn & 63);
        dst = g_ws + WQKV_OFF + f * 8;
    } else {
        int fo = f - 3072;
        int m = fo >> 9;
        int fi = fo & 511;
        int nt = fi >> 7, ks = (fi >> 6) & 1, l = fi & 63;
        int nn = nt * 16 + (l & 15);
        int kb = ks * 32 + ((l >> 4) & 3) * 8;
        src = (m ? Wo2 : Wo1) + kb * 64 + nn;
        dst = g_ws + (m ? WO2_OFF : WO1_OFF) + fi * 8;
    }
    #pragma unroll
    for (int j = 0; j < 8; ++j) dst[j] = f2bf(src[j * 64]);
}

// LDS layout (tight, 24-row buffers; padding-row reads over-read by design):
//  [0,     6528)  sh_h   u16 [24][136]   (sh_tmp overlays this after Phase C)
//  [6528,  9984)  sh_o   u16 [24][72]
//  [9984, 16512)  sh_q   f32 [24][68]
//  [16512,23040)  sh_k   f32 [24][68]
//  [23040,29568)  sh_v   f32 [24][68]
#define SMEM_BYTES 29568

__global__ __launch_bounds__(256, 5) void ta_mfma(
    const float* __restrict__ x,   const float* __restrict__ ste,
    const float* __restrict__ bq,  const float* __restrict__ bk,
    const float* __restrict__ bv,  const float* __restrict__ bo1,
    const float* __restrict__ bo2, float* __restrict__ out)
{
    __shared__ __align__(16) char smem[SMEM_BYTES];
    u16*   sh_h   = (u16*)smem;
    u16*   sh_tmp = (u16*)smem;            // overlays sh_h (dead after Phase B)
    u16*   sh_o   = (u16*)(smem + 6528);
    float* sh_q   = (float*)(smem + 9984);
    float* sh_k   = (float*)(smem + 16512);
    float* sh_v   = (float*)(smem + 23040);

    const int tid  = threadIdx.x;
    const int w    = tid >> 6;
    const int l    = tid & 63;
    const int l15  = l & 15;
    const int quad = l >> 4;
    const int n = blockIdx.x;
    const int b = blockIdx.y;

    // ---------------- Phase A: stage h rows 0..23 (fp32 -> bf16) ----------------
    for (int i = tid; i < 384; i += 256) {
        int f = i * 8;
        int t = f >> 7, kk = f & 127;
        int gbase = ((b * T_ + t) * N_ + n) * D_;
        const float* src = (kk < 64) ? (x + gbase + kk) : (ste + gbase + kk - 64);
        float4 a = *(const float4*)src;
        float4 c = *(const float4*)(src + 4);
        uint4 o;
        o.x = pack2(a.x, a.y); o.y = pack2(a.z, a.w);
        o.z = pack2(c.x, c.y); o.w = pack2(c.z, c.w);
        *(uint4*)(sh_h + t * 136 + kk) = o;
    }
    const int col16 = w * 16 + l15;
    float bqv = bq[col16],  bkv = bk[col16],  bvv = bv[col16];
    float b1v = bo1[col16], b2v = bo2[col16];
    __syncthreads();

    // ---------------- Phase B: qkv = relu(h @ Wqkv + b) via MFMA ----------------
    // A-frags: rows 16+l15 for l15>=8 over-read past sh_h's 24 rows into sh_o;
    // those MFMA output rows are never stored (guards below).
    bf16x8 af0_0 = *(const bf16x8*)(sh_h + l15 * 136 + 0  + quad * 8);
    bf16x8 af0_1 = *(const bf16x8*)(sh_h + l15 * 136 + 32 + quad * 8);
    bf16x8 af0_2 = *(const bf16x8*)(sh_h + l15 * 136 + 64 + quad * 8);
    bf16x8 af0_3 = *(const bf16x8*)(sh_h + l15 * 136 + 96 + quad * 8);
    bf16x8 af1_0 = *(const bf16x8*)(sh_h + (16 + l15) * 136 + 0  + quad * 8);
    bf16x8 af1_1 = *(const bf16x8*)(sh_h + (16 + l15) * 136 + 32 + quad * 8);
    bf16x8 af1_2 = *(const bf16x8*)(sh_h + (16 + l15) * 136 + 64 + quad * 8);
    bf16x8 af1_3 = *(const bf16x8*)(sh_h + (16 + l15) * 136 + 96 + quad * 8);

    // --- Q (nt = w) ---
    {
        const int nt = w;
        f32x4 c0 = {0.f,0.f,0.f,0.f}, c1 = {0.f,0.f,0.f,0.f};
        bf16x8 bf;
        bf = *(const bf16x8*)(g_ws + WQKV_OFF + ((nt*4 + 0)*64 + l)*8);
        c0 = __builtin_amdgcn_mfma_f32_16x16x32_bf16(af0_0, bf, c0, 0,0,0);
        c1 = __builtin_amdgcn_mfma_f32_16x16x32_bf16(af1_0, bf, c1, 0,0,0);
        bf = *(const bf16x8*)(g_ws + WQKV_OFF + ((nt*4 + 1)*64 + l)*8);
        c0 = __builtin_amdgcn_mfma_f32_16x16x32_bf16(af0_1, bf, c0, 0,0,0);
        c1 = __builtin_amdgcn_mfma_f32_16x16x32_bf16(af1_1, bf, c1, 0,0,0);
        bf = *(const bf16x8*)(g_ws + WQKV_OFF + ((nt*4 + 2)*64 + l)*8);
        c0 = __builtin_amdgcn_mfma_f32_16x16x32_bf16(af0_2, bf, c0, 0,0,0);
        c1 = __builtin_amdgcn_mfma_f32_16x16x32_bf16(af1_2, bf, c1, 0,0,0);
        bf = *(const bf16x8*)(g_ws + WQKV_OFF + ((nt*4 + 3)*64 + l)*8);
        c0 = __builtin_amdgcn_mfma_f32_16x16x32_bf16(af0_3, bf, c0, 0,0,0);
        c1 = __builtin_amdgcn_mfma_f32_16x16x32_bf16(af1_3, bf, c1, 0,0,0);
        #pragma unroll
        for (int r = 0; r < 4; ++r) {
            int row0 = quad * 4 + r;
            sh_q[row0 * 68 + col16] = fmaxf(c0[r] + bqv, 0.f);
        }
        if (quad < 2) {
            #pragma unroll
            for (int r = 0; r < 4; ++r) {
                int row1 = 16 + quad * 4 + r;   // 16..23
                sh_q[row1 * 68 + col16] = fmaxf(c1[r] + bqv, 0.f);
            }
        }
    }
    // --- K (nt = w + 4) ---
    {
        const int nt = w + 4;
        f32x4 c0 = {0.f,0.f,0.f,0.f}, c1 = {0.f,0.f,0.f,0.f};
        bf16x8 bf;
        bf = *(const bf16x8*)(g_ws + WQKV_OFF + ((nt*4 + 0)*64 + l)*8);
        c0 = __builtin_amdgcn_mfma_f32_16x16x32_bf16(af0_0, bf, c0, 0,0,0);
        c1 = __builtin_amdgcn_mfma_f32_16x16x32_bf16(af1_0, bf, c1, 0,0,0);
        bf = *(const bf16x8*)(g_ws + WQKV_OFF + ((nt*4 + 1)*64 + l)*8);
        c0 = __builtin_amdgcn_mfma_f32_16x16x32_bf16(af0_1, bf, c0, 0,0,0);
        c1 = __builtin_amdgcn_mfma_f32_16x16x32_bf16(af1_1, bf, c1, 0,0,0);
        bf = *(const bf16x8*)(g_ws + WQKV_OFF + ((nt*4 + 2)*64 + l)*8);
        c0 = __builtin_amdgcn_mfma_f32_16x16x32_bf16(af0_2, bf, c0, 0,0,0);
        c1 = __builtin_amdgcn_mfma_f32_16x16x32_bf16(af1_2, bf, c1, 0,0,0);
        bf = *(const bf16x8*)(g_ws + WQKV_OFF + ((nt*4 + 3)*64 + l)*8);
        c0 = __builtin_amdgcn_mfma_f32_16x16x32_bf16(af0_3, bf, c0, 0,0,0);
        c1 = __builtin_amdgcn_mfma_f32_16x16x32_bf16(af1_3, bf, c1, 0,0,0);
        #pragma unroll
        for (int r = 0; r < 4; ++r) {
            int row0 = quad * 4 + r;
            sh_k[row0 * 68 + col16] = fmaxf(c0[r] + bkv, 0.f);
        }
        if (quad < 2) {
            #pragma unroll
            for (int r = 0; r < 4; ++r) {
                int row1 = 16 + quad * 4 + r;
                sh_k[row1 * 68 + col16] = fmaxf(c1[r] + bkv, 0.f);
            }
        }
    }
    // --- V (nt = w + 8) ---
    {
        const int nt = w + 8;
        f32x4 c0 = {0.f,0.f,0.f,0.f}, c1 = {0.f,0.f,0.f,0.f};
        bf16x8 bf;
        bf = *(const bf16x8*)(g_ws + WQKV_OFF + ((nt*4 + 0)*64 + l)*8);
        c0 = __builtin_amdgcn_mfma_f32_16x16x32_bf16(af0_0, bf, c0, 0,0,0);
        c1 = __builtin_amdgcn_mfma_f32_16x16x32_bf16(af1_0, bf, c1, 0,0,0);
        bf = *(const bf16x8*)(g_ws + WQKV_OFF + ((nt*4 + 1)*64 + l)*8);
        c0 = __builtin_amdgcn_mfma_f32_16x16x32_bf16(af0_1, bf, c0, 0,0,0);
        c1 = __builtin_amdgcn_mfma_f32_16x16x32_bf16(af1_1, bf, c1, 0,0,0);
        bf = *(const bf16x8*)(g_ws + WQKV_OFF + ((nt*4 + 2)*64 + l)*8);
        c0 = __builtin_amdgcn_mfma_f32_16x16x32_bf16(af0_2, bf, c0, 0,0,0);
        c1 = __builtin_amdgcn_mfma_f32_16x16x32_bf16(af1_2, bf, c1, 0,0,0);
        bf = *(const bf16x8*)(g_ws + WQKV_OFF + ((nt*4 + 3)*64 + l)*8);
        c0 = __builtin_amdgcn_mfma_f32_16x16x32_bf16(af0_3, bf, c0, 0,0,0);
        c1 = __builtin_amdgcn_mfma_f32_16x16x32_bf16(af1_3, bf, c1, 0,0,0);
        #pragma unroll
        for (int r = 0; r < 4; ++r) {
            int row0 = quad * 4 + r;
            sh_v[row0 * 68 + col16] = fmaxf(c0[r] + bvv, 0.f);
        }
        if (quad < 2) {
            #pragma unroll
            for (int r = 0; r < 4; ++r) {
                int row1 = 16 + quad * 4 + r;
                sh_v[row1 * 68 + col16] = fmaxf(c1[r] + bvv, 0.f);
            }
        }
    }
    __syncthreads();

    // ---------------- Phase C: attention (VALU) + FC B-frag prefetch ----------------
    bf16x8 w1f0 = *(const bf16x8*)(g_ws + WO1_OFF + ((w*2 + 0)*64 + l)*8);
    bf16x8 w1f1 = *(const bf16x8*)(g_ws + WO1_OFF + ((w*2 + 1)*64 + l)*8);
    bf16x8 w2f0 = *(const bf16x8*)(g_ws + WO2_OFF + ((w*2 + 0)*64 + l)*8);
    bf16x8 w2f1 = *(const bf16x8*)(g_ws + WO2_OFF + ((w*2 + 1)*64 + l)*8);
    {
        const int hi = tid >> 5;
        const int t  = tid & 31;
        if (t < 24) {
            const float* qp = sh_q + t * 68 + hi * 8;
            float qr[8];
            #pragma unroll
            for (int d = 0; d < 8; ++d) qr[d] = qp[d] * 0.35355339059327373f;
            float e[24], mx = -3.0e38f;
            #pragma unroll
            for (int s = 0; s < T_; ++s) {
                const float* kp = sh_k + s * 68 + hi * 8;
                float4 ka = *(const float4*)kp;
                float4 kb2 = *(const float4*)(kp + 4);
                float dot = qr[0] * ka.x;
                dot = fmaf(qr[1], ka.y, dot);  dot = fmaf(qr[2], ka.z, dot);
                dot = fmaf(qr[3], ka.w, dot);  dot = fmaf(qr[4], kb2.x, dot);
                dot = fmaf(qr[5], kb2.y, dot); dot = fmaf(qr[6], kb2.z, dot);
                dot = fmaf(qr[7], kb2.w, dot);
                float lg = (s <= t) ? dot : -32767.0f;
                e[s] = lg;
                mx = fmaxf(mx, lg);
            }
            float sum = 0.f;
            #pragma unroll
            for (int s = 0; s < T_; ++s) { float ee = __expf(e[s] - mx); e[s] = ee; sum += ee; }
            float inv = 1.0f / sum;
            float ov[8];
            #pragma unroll
            for (int d = 0; d < 8; ++d) ov[d] = 0.f;
            #pragma unroll
            for (int s = 0; s < T_; ++s) {
                float p = e[s] * inv;
                const float* vp = sh_v + s * 68 + hi * 8;
                float4 va = *(const float4*)vp;
                float4 vb = *(const float4*)(vp + 4);
                ov[0] = fmaf(p, va.x, ov[0]); ov[1] = fmaf(p, va.y, ov[1]);
                ov[2] = fmaf(p, va.z, ov[2]); ov[3] = fmaf(p, va.w, ov[3]);
                ov[4] = fmaf(p, vb.x, ov[4]); ov[5] = fmaf(p, vb.y, ov[5]);
                ov[6] = fmaf(p, vb.z, ov[6]); ov[7] = fmaf(p, vb.w, ov[7]);
            }
            u16* op = sh_o + t * 72 + hi * 8;
            *(u32*)(op + 0) = pack2(ov[0], ov[1]);
            *(u32*)(op + 2) = pack2(ov[2], ov[3]);
            *(u32*)(op + 4) = pack2(ov[4], ov[5]);
            *(u32*)(op + 6) = pack2(ov[6], ov[7]);
        }
    }
    __syncthreads();

    // ---------------- Phase D1: tmp = relu(o @ Wo1 + bo1) ----------------
    // a10/a11 rows 24..31 over-read past sh_o into sh_q; output rows guarded.
    {
        bf16x8 a00 = *(const bf16x8*)(sh_o + l15 * 72 + 0  + quad * 8);
        bf16x8 a01 = *(const bf16x8*)(sh_o + l15 * 72 + 32 + quad * 8);
        bf16x8 a10 = *(const bf16x8*)(sh_o + (16 + l15) * 72 + 0  + quad * 8);
        bf16x8 a11 = *(const bf16x8*)(sh_o + (16 + l15) * 72 + 32 + quad * 8);
        f32x4 c0 = {0.f,0.f,0.f,0.f}, c1 = {0.f,0.f,0.f,0.f};
        c0 = __builtin_amdgcn_mfma_f32_16x16x32_bf16(a00, w1f0, c0, 0,0,0);
        c1 = __builtin_amdgcn_mfma_f32_16x16x32_bf16(a10, w1f0, c1, 0,0,0);
        c0 = __builtin_amdgcn_mfma_f32_16x16x32_bf16(a01, w1f1, c0, 0,0,0);
        c1 = __builtin_amdgcn_mfma_f32_16x16x32_bf16(a11, w1f1, c1, 0,0,0);
        __syncthreads();   // sh_tmp overlays sh_h; (no pending sh_h readers: A-frags long consumed)
        #pragma unroll
        for (int r = 0; r < 4; ++r) {
            int row0 = quad * 4 + r;
            sh_tmp[row0 * 72 + col16] = f2bf(fmaxf(c0[r] + b1v, 0.f));
        }
        if (quad < 2) {
            #pragma unroll
            for (int r = 0; r < 4; ++r) {
                int row1 = 16 + quad * 4 + r;
                sh_tmp[row1 * 72 + col16] = f2bf(fmaxf(c1[r] + b1v, 0.f));
            }
        }
    }
    __syncthreads();

    // ---------------- Phase D2: out = tmp @ Wo2 + bo2 -> global (fp32) ----------------
    {
        bf16x8 a00 = *(const bf16x8*)(sh_tmp + l15 * 72 + 0  + quad * 8);
        bf16x8 a01 = *(const bf16x8*)(sh_tmp + l15 * 72 + 32 + quad * 8);
        bf16x8 a10 = *(const bf16x8*)(sh_tmp + (16 + l15) * 72 + 0  + quad * 8);
        bf16x8 a11 = *(const bf16x8*)(sh_tmp + (16 + l15) * 72 + 32 + quad * 8);
        f32x4 c0 = {0.f,0.f,0.f,0.f}, c1 = {0.f,0.f,0.f,0.f};
        c0 = __builtin_amdgcn_mfma_f32_16x16x32_bf16(a00, w2f0, c0, 0,0,0);
        c1 = __builtin_amdgcn_mfma_f32_16x16x32_bf16(a10, w2f0, c1, 0,0,0);
        c0 = __builtin_amdgcn_mfma_f32_16x16x32_bf16(a01, w2f1, c0, 0,0,0);
        c1 = __builtin_amdgcn_mfma_f32_16x16x32_bf16(a11, w2f1, c1, 0,0,0);
        #pragma unroll
        for (int r = 0; r < 4; ++r) {
            int row0 = quad * 4 + r;
            out[((b * T_ + row0) * N_ + n) * D_ + col16] = c0[r] + b2v;
            int row1 = 16 + row0;
            if (row1 < T_)
                out[((b * T_ + row1) * N_ + n) * D_ + col16] = c1[r] + b2v;
        }
    }
}

extern "C" void kernel_launch(void* const* d_in, const int* in_sizes, int n_in,
                              void* d_out, int out_size, void* d_ws, size_t ws_size,
                              hipStream_t stream) {
    (void)in_sizes; (void)n_in; (void)out_size; (void)d_ws; (void)ws_size;
    const float* x   = (const float*)d_in[0];
    const float* ste = (const float*)d_in[1];
    const float* Wq  = (const float*)d_in[2];
    const float* bq  = (const float*)d_in[3];
    const float* Wk  = (const float*)d_in[4];
    const float* bk  = (const float*)d_in[5];
    const float* Wv  = (const float*)d_in[6];
    const float* bv  = (const float*)d_in[7];
    const float* Wo1 = (const float*)d_in[8];
    const float* bo1 = (const float*)d_in[9];
    const float* Wo2 = (const float*)d_in[10];
    const float* bo2 = (const float*)d_in[11];

    ta_repack<<<dim3(16), dim3(256), 0, stream>>>(Wq, Wk, Wv, Wo1, Wo2);
    ta_mfma<<<dim3(N_, B_), dim3(256), 0, stream>>>(
        x, ste, bq, bk, bv, bo1, bo2, (float*)d_out);
}

// Round 2
// 234.332 us; speedup vs baseline: 1.0816x; 1.0816x over previous
//
#include <hip/hip_runtime.h>
#include <hip/hip_bf16.h>

// Round 9: r8's occupancy gain was cancelled by scratch spills:
// __launch_bounds__(256,5) pushed VGPR 84->48 and e[24]/ov[8] spilled
// (WRITE_SIZE 62->163MB = scratch traffic). This round:
//  - plain __launch_bounds__(256): natural ~84 VGPR, no spill (r7-proven),
//    LDS stays 29696B so occupancy ~16 waves/CU (VGPR-step-bound).
//  - Phase C remapped t=p%24, hi=p/24 (p=tid<192): 3 fully-active waves +
//    1 idle wave instead of 4 waves at 75% lanes -> 25% fewer phase-C
//    wave-instruction issues.
//  - Wo1/Wo2 fragment prefetch moved AFTER the attention barrier: 16 fewer
//    live VGPRs across the attention phase (g_ws is L2-hot, latency hidden).

typedef unsigned short u16;
typedef unsigned int u32;
typedef __attribute__((ext_vector_type(8))) short bf16x8;
typedef __attribute__((ext_vector_type(4))) float f32x4;

#define B_ 32
#define T_ 24
#define N_ 325
#define D_ 64

#define WQKV_OFF 0        // 3072 frags * 8 el = 24576 el
#define WO1_OFF  24576    // 512 frags  * 8 el = 4096 el
#define WO2_OFF  28672    // 512 frags  * 8 el = 4096 el
#define WS_ELS   32768

__device__ __align__(64) u16 g_ws[WS_ELS];

__device__ __forceinline__ u16 f2bf(float f) {
    u32 u = __float_as_uint(f);
    return (u16)((u + 0x7FFFu + ((u >> 16) & 1u)) >> 16);  // RNE
}
__device__ __forceinline__ u32 pack2(float a, float b) {
    return (u32)f2bf(a) | ((u32)f2bf(b) << 16);
}

// B-frag (16x16x32): lane l holds B[k = ks*32 + (l>>4)*8 + j][n = nt*16 + (l&15)]
__global__ void ta_repack(const float* __restrict__ Wq, const float* __restrict__ Wk,
                          const float* __restrict__ Wv, const float* __restrict__ Wo1,
                          const float* __restrict__ Wo2) {
    int f = blockIdx.x * 256 + threadIdx.x;   // 0..4095
    const float* src;
    u16* dst;
    if (f < 3072) {
        int nt = f >> 8, ks = (f >> 6) & 3, l = f & 63;
        int nn = nt * 16 + (l & 15);
        int kb = ks * 32 + ((l >> 4) & 3) * 8;
        const float* W = (nn < 64) ? Wq : (nn < 128 ? Wk : Wv);
        src = W + kb * 64 + (nn & 63);
        dst = g_ws + WQKV_OFF + f * 8;
    } else {
        int fo = f - 3072;
        int m = fo >> 9;
        int fi = fo & 511;
        int nt = fi >> 7, ks = (fi >> 6) & 1, l = fi & 63;
        int nn = nt * 16 + (l & 15);
        int kb = ks * 32 + ((l >> 4) & 3) * 8;
        src = (m ? Wo2 : Wo1) + kb * 64 + nn;
        dst = g_ws + (m ? WO2_OFF : WO1_OFF) + fi * 8;
    }
    #pragma unroll
    for (int j = 0; j < 8; ++j) dst[j] = f2bf(src[j * 64]);
}

// LDS layout (tight, 24-row buffers; padding-row reads over-read by design):
//  [0,     6528)  sh_h   u16 [24][136]   (sh_tmp overlays this after Phase C)
//  [6528,  9984)  sh_o   u16 [24][72]
//  [9984, 16512)  sh_q   f32 [24][68]
//  [16512,23040)  sh_k   f32 [24][68]
//  [23040,29568)  sh_v   f32 [24][68]
#define SMEM_BYTES 29568

__global__ __launch_bounds__(256) void ta_mfma(
    const float* __restrict__ x,   const float* __restrict__ ste,
    const float* __restrict__ bq,  const float* __restrict__ bk,
    const float* __restrict__ bv,  const float* __restrict__ bo1,
    const float* __restrict__ bo2, float* __restrict__ out)
{
    __shared__ __align__(16) char smem[SMEM_BYTES];
    u16*   sh_h   = (u16*)smem;
    u16*   sh_tmp = (u16*)smem;            // overlays sh_h (dead after Phase B)
    u16*   sh_o   = (u16*)(smem + 6528);
    float* sh_q   = (float*)(smem + 9984);
    float* sh_k   = (float*)(smem + 16512);
    float* sh_v   = (float*)(smem + 23040);

    const int tid  = threadIdx.x;
    const int w    = tid >> 6;
    const int l    = tid & 63;
    const int l15  = l & 15;
    const int quad = l >> 4;
    const int n = blockIdx.x;
    const int b = blockIdx.y;

    // ---------------- Phase A: stage h rows 0..23 (fp32 -> bf16) ----------------
    for (int i = tid; i < 384; i += 256) {
        int f = i * 8;
        int t = f >> 7, kk = f & 127;
        int gbase = ((b * T_ + t) * N_ + n) * D_;
        const float* src = (kk < 64) ? (x + gbase + kk) : (ste + gbase + kk - 64);
        float4 a = *(const float4*)src;
        float4 c = *(const float4*)(src + 4);
        uint4 o;
        o.x = pack2(a.x, a.y); o.y = pack2(a.z, a.w);
        o.z = pack2(c.x, c.y); o.w = pack2(c.z, c.w);
        *(uint4*)(sh_h + t * 136 + kk) = o;
    }
    const int col16 = w * 16 + l15;
    float bqv = bq[col16],  bkv = bk[col16],  bvv = bv[col16];
    float b1v = bo1[col16], b2v = bo2[col16];
    __syncthreads();

    // ---------------- Phase B: qkv = relu(h @ Wqkv + b) via MFMA ----------------
    // A-frags: rows 16+l15 for l15>=8 over-read past sh_h's 24 rows into sh_o;
    // those MFMA output rows are never stored (guards below).
    bf16x8 af0_0 = *(const bf16x8*)(sh_h + l15 * 136 + 0  + quad * 8);
    bf16x8 af0_1 = *(const bf16x8*)(sh_h + l15 * 136 + 32 + quad * 8);
    bf16x8 af0_2 = *(const bf16x8*)(sh_h + l15 * 136 + 64 + quad * 8);
    bf16x8 af0_3 = *(const bf16x8*)(sh_h + l15 * 136 + 96 + quad * 8);
    bf16x8 af1_0 = *(const bf16x8*)(sh_h + (16 + l15) * 136 + 0  + quad * 8);
    bf16x8 af1_1 = *(const bf16x8*)(sh_h + (16 + l15) * 136 + 32 + quad * 8);
    bf16x8 af1_2 = *(const bf16x8*)(sh_h + (16 + l15) * 136 + 64 + quad * 8);
    bf16x8 af1_3 = *(const bf16x8*)(sh_h + (16 + l15) * 136 + 96 + quad * 8);

    // --- Q (nt = w) ---
    {
        const int nt = w;
        f32x4 c0 = {0.f,0.f,0.f,0.f}, c1 = {0.f,0.f,0.f,0.f};
        bf16x8 bf;
        bf = *(const bf16x8*)(g_ws + WQKV_OFF + ((nt*4 + 0)*64 + l)*8);
        c0 = __builtin_amdgcn_mfma_f32_16x16x32_bf16(af0_0, bf, c0, 0,0,0);
        c1 = __builtin_amdgcn_mfma_f32_16x16x32_bf16(af1_0, bf, c1, 0,0,0);
        bf = *(const bf16x8*)(g_ws + WQKV_OFF + ((nt*4 + 1)*64 + l)*8);
        c0 = __builtin_amdgcn_mfma_f32_16x16x32_bf16(af0_1, bf, c0, 0,0,0);
        c1 = __builtin_amdgcn_mfma_f32_16x16x32_bf16(af1_1, bf, c1, 0,0,0);
        bf = *(const bf16x8*)(g_ws + WQKV_OFF + ((nt*4 + 2)*64 + l)*8);
        c0 = __builtin_amdgcn_mfma_f32_16x16x32_bf16(af0_2, bf, c0, 0,0,0);
        c1 = __builtin_amdgcn_mfma_f32_16x16x32_bf16(af1_2, bf, c1, 0,0,0);
        bf = *(const bf16x8*)(g_ws + WQKV_OFF + ((nt*4 + 3)*64 + l)*8);
        c0 = __builtin_amdgcn_mfma_f32_16x16x32_bf16(af0_3, bf, c0, 0,0,0);
        c1 = __builtin_amdgcn_mfma_f32_16x16x32_bf16(af1_3, bf, c1, 0,0,0);
        #pragma unroll
        for (int r = 0; r < 4; ++r) {
            int row0 = quad * 4 + r;
            sh_q[row0 * 68 + col16] = fmaxf(c0[r] + bqv, 0.f);
        }
        if (quad < 2) {
            #pragma unroll
            for (int r = 0; r < 4; ++r) {
                int row1 = 16 + quad * 4 + r;   // 16..23
                sh_q[row1 * 68 + col16] = fmaxf(c1[r] + bqv, 0.f);
            }
        }
    }
    // --- K (nt = w + 4) ---
    {
        const int nt = w + 4;
        f32x4 c0 = {0.f,0.f,0.f,0.f}, c1 = {0.f,0.f,0.f,0.f};
        bf16x8 bf;
        bf = *(const bf16x8*)(g_ws + WQKV_OFF + ((nt*4 + 0)*64 + l)*8);
        c0 = __builtin_amdgcn_mfma_f32_16x16x32_bf16(af0_0, bf, c0, 0,0,0);
        c1 = __builtin_amdgcn_mfma_f32_16x16x32_bf16(af1_0, bf, c1, 0,0,0);
        bf = *(const bf16x8*)(g_ws + WQKV_OFF + ((nt*4 + 1)*64 + l)*8);
        c0 = __builtin_amdgcn_mfma_f32_16x16x32_bf16(af0_1, bf, c0, 0,0,0);
        c1 = __builtin_amdgcn_mfma_f32_16x16x32_bf16(af1_1, bf, c1, 0,0,0);
        bf = *(const bf16x8*)(g_ws + WQKV_OFF + ((nt*4 + 2)*64 + l)*8);
        c0 = __builtin_amdgcn_mfma_f32_16x16x32_bf16(af0_2, bf, c0, 0,0,0);
        c1 = __builtin_amdgcn_mfma_f32_16x16x32_bf16(af1_2, bf, c1, 0,0,0);
        bf = *(const bf16x8*)(g_ws + WQKV_OFF + ((nt*4 + 3)*64 + l)*8);
        c0 = __builtin_amdgcn_mfma_f32_16x16x32_bf16(af0_3, bf, c0, 0,0,0);
        c1 = __builtin_amdgcn_mfma_f32_16x16x32_bf16(af1_3, bf, c1, 0,0,0);
        #pragma unroll
        for (int r = 0; r < 4; ++r) {
            int row0 = quad * 4 + r;
            sh_k[row0 * 68 + col16] = fmaxf(c0[r] + bkv, 0.f);
        }
        if (quad < 2) {
            #pragma unroll
            for (int r = 0; r < 4; ++r) {
                int row1 = 16 + quad * 4 + r;
                sh_k[row1 * 68 + col16] = fmaxf(c1[r] + bkv, 0.f);
            }
        }
    }
    // --- V (nt = w + 8) ---
    {
        const int nt = w + 8;
        f32x4 c0 = {0.f,0.f,0.f,0.f}, c1 = {0.f,0.f,0.f,0.f};
        bf16x8 bf;
        bf = *(const bf16x8*)(g_ws + WQKV_OFF + ((nt*4 + 0)*64 + l)*8);
        c0 = __builtin_amdgcn_mfma_f32_16x16x32_bf16(af0_0, bf, c0, 0,0,0);
        c1 = __builtin_amdgcn_mfma_f32_16x16x32_bf16(af1_0, bf, c1, 0,0,0);
        bf = *(const bf16x8*)(g_ws + WQKV_OFF + ((nt*4 + 1)*64 + l)*8);
        c0 = __builtin_amdgcn_mfma_f32_16x16x32_bf16(af0_1, bf, c0, 0,0,0);
        c1 = __builtin_amdgcn_mfma_f32_16x16x32_bf16(af1_1, bf, c1, 0,0,0);
        bf = *(const bf16x8*)(g_ws + WQKV_OFF + ((nt*4 + 2)*64 + l)*8);
        c0 = __builtin_amdgcn_mfma_f32_16x16x32_bf16(af0_2, bf, c0, 0,0,0);
        c1 = __builtin_amdgcn_mfma_f32_16x16x32_bf16(af1_2, bf, c1, 0,0,0);
        bf = *(const bf16x8*)(g_ws + WQKV_OFF + ((nt*4 + 3)*64 + l)*8);
        c0 = __builtin_amdgcn_mfma_f32_16x16x32_bf16(af0_3, bf, c0, 0,0,0);
        c1 = __builtin_amdgcn_mfma_f32_16x16x32_bf16(af1_3, bf, c1, 0,0,0);
        #pragma unroll
        for (int r = 0; r < 4; ++r) {
            int row0 = quad * 4 + r;
            sh_v[row0 * 68 + col16] = fmaxf(c0[r] + bvv, 0.f);
        }
        if (quad < 2) {
            #pragma unroll
            for (int r = 0; r < 4; ++r) {
                int row1 = 16 + quad * 4 + r;
                sh_v[row1 * 68 + col16] = fmaxf(c1[r] + bvv, 0.f);
            }
        }
    }
    __syncthreads();

    // ---------------- Phase C: attention (VALU), 3 fully-active waves ----------------
    {
        const int p = tid;
        if (p < 192) {
            const int t  = p % 24;
            const int hi = p / 24;
            const float* qp = sh_q + t * 68 + hi * 8;
            float qr[8];
            #pragma unroll
            for (int d = 0; d < 8; ++d) qr[d] = qp[d] * 0.35355339059327373f;
            float e[24], mx = -3.0e38f;
            #pragma unroll
            for (int s = 0; s < T_; ++s) {
                const float* kp = sh_k + s * 68 + hi * 8;
                float4 ka = *(const float4*)kp;
                float4 kb2 = *(const float4*)(kp + 4);
                float dot = qr[0] * ka.x;
                dot = fmaf(qr[1], ka.y, dot);  dot = fmaf(qr[2], ka.z, dot);
                dot = fmaf(qr[3], ka.w, dot);  dot = fmaf(qr[4], kb2.x, dot);
                dot = fmaf(qr[5], kb2.y, dot); dot = fmaf(qr[6], kb2.z, dot);
                dot = fmaf(qr[7], kb2.w, dot);
                float lg = (s <= t) ? dot : -32767.0f;
                e[s] = lg;
                mx = fmaxf(mx, lg);
            }
            float sum = 0.f;
            #pragma unroll
            for (int s = 0; s < T_; ++s) { float ee = __expf(e[s] - mx); e[s] = ee; sum += ee; }
            float inv = 1.0f / sum;
            float ov[8];
            #pragma unroll
            for (int d = 0; d < 8; ++d) ov[d] = 0.f;
            #pragma unroll
            for (int s = 0; s < T_; ++s) {
                float p2 = e[s] * inv;
                const float* vp = sh_v + s * 68 + hi * 8;
                float4 va = *(const float4*)vp;
                float4 vb = *(const float4*)(vp + 4);
                ov[0] = fmaf(p2, va.x, ov[0]); ov[1] = fmaf(p2, va.y, ov[1]);
                ov[2] = fmaf(p2, va.z, ov[2]); ov[3] = fmaf(p2, va.w, ov[3]);
                ov[4] = fmaf(p2, vb.x, ov[4]); ov[5] = fmaf(p2, vb.y, ov[5]);
                ov[6] = fmaf(p2, vb.z, ov[6]); ov[7] = fmaf(p2, vb.w, ov[7]);
            }
            u16* op = sh_o + t * 72 + hi * 8;
            *(u32*)(op + 0) = pack2(ov[0], ov[1]);
            *(u32*)(op + 2) = pack2(ov[2], ov[3]);
            *(u32*)(op + 4) = pack2(ov[4], ov[5]);
            *(u32*)(op + 6) = pack2(ov[6], ov[7]);
        }
    }
    __syncthreads();

    // ---------------- Phase D1: tmp = relu(o @ Wo1 + bo1) ----------------
    // Wo1/Wo2 B-frags loaded here (post-attention) to keep attention-phase
    // register pressure low; g_ws is L2-hot, latency hidden by other blocks.
    bf16x8 w1f0 = *(const bf16x8*)(g_ws + WO1_OFF + ((w*2 + 0)*64 + l)*8);
    bf16x8 w1f1 = *(const bf16x8*)(g_ws + WO1_OFF + ((w*2 + 1)*64 + l)*8);
    bf16x8 w2f0 = *(const bf16x8*)(g_ws + WO2_OFF + ((w*2 + 0)*64 + l)*8);
    bf16x8 w2f1 = *(const bf16x8*)(g_ws + WO2_OFF + ((w*2 + 1)*64 + l)*8);
    // a10/a11 rows 24..31 over-read past sh_o into sh_q; output rows guarded.
    {
        bf16x8 a00 = *(const bf16x8*)(sh_o + l15 * 72 + 0  + quad * 8);
        bf16x8 a01 = *(const bf16x8*)(sh_o + l15 * 72 + 32 + quad * 8);
        bf16x8 a10 = *(const bf16x8*)(sh_o + (16 + l15) * 72 + 0  + quad * 8);
        bf16x8 a11 = *(const bf16x8*)(sh_o + (16 + l15) * 72 + 32 + quad * 8);
        f32x4 c0 = {0.f,0.f,0.f,0.f}, c1 = {0.f,0.f,0.f,0.f};
        c0 = __builtin_amdgcn_mfma_f32_16x16x32_bf16(a00, w1f0, c0, 0,0,0);
        c1 = __builtin_amdgcn_mfma_f32_16x16x32_bf16(a10, w1f0, c1, 0,0,0);
        c0 = __builtin_amdgcn_mfma_f32_16x16x32_bf16(a01, w1f1, c0, 0,0,0);
        c1 = __builtin_amdgcn_mfma_f32_16x16x32_bf16(a11, w1f1, c1, 0,0,0);
        __syncthreads();   // sh_tmp overlays sh_h; (no pending sh_h readers: A-frags long consumed)
        #pragma unroll
        for (int r = 0; r < 4; ++r) {
            int row0 = quad * 4 + r;
            sh_tmp[row0 * 72 + col16] = f2bf(fmaxf(c0[r] + b1v, 0.f));
        }
        if (quad < 2) {
            #pragma unroll
            for (int r = 0; r < 4; ++r) {
                int row1 = 16 + quad * 4 + r;
                sh_tmp[row1 * 72 + col16] = f2bf(fmaxf(c1[r] + b1v, 0.f));
            }
        }
    }
    __syncthreads();

    // ---------------- Phase D2: out = tmp @ Wo2 + bo2 -> global (fp32) ----------------
    {
        bf16x8 a00 = *(const bf16x8*)(sh_tmp + l15 * 72 + 0  + quad * 8);
        bf16x8 a01 = *(const bf16x8*)(sh_tmp + l15 * 72 + 32 + quad * 8);
        bf16x8 a10 = *(const bf16x8*)(sh_tmp + (16 + l15) * 72 + 0  + quad * 8);
        bf16x8 a11 = *(const bf16x8*)(sh_tmp + (16 + l15) * 72 + 32 + quad * 8);
        f32x4 c0 = {0.f,0.f,0.f,0.f}, c1 = {0.f,0.f,0.f,0.f};
        c0 = __builtin_amdgcn_mfma_f32_16x16x32_bf16(a00, w2f0, c0, 0,0,0);
        c1 = __builtin_amdgcn_mfma_f32_16x16x32_bf16(a10, w2f0, c1, 0,0,0);
        c0 = __builtin_amdgcn_mfma_f32_16x16x32_bf16(a01, w2f1, c0, 0,0,0);
        c1 = __builtin_amdgcn_mfma_f32_16x16x32_bf16(a11, w2f1, c1, 0,0,0);
        #pragma unroll
        for (int r = 0; r < 4; ++r) {
            int row0 = quad * 4 + r;
            out[((b * T_ + row0) * N_ + n) * D_ + col16] = c0[r] + b2v;
            int row1 = 16 + row0;
            if (row1 < T_)
                out[((b * T_ + row1) * N_ + n) * D_ + col16] = c1[r] + b2v;
        }
    }
}

extern "C" void kernel_launch(void* const* d_in, const int* in_sizes, int n_in,
                              void* d_out, int out_size, void* d_ws, size_t ws_size,
                              hipStream_t stream) {
    (void)in_sizes; (void)n_in; (void)out_size; (void)d_ws; (void)ws_size;
    const float* x   = (const float*)d_in[0];
    const float* ste = (const float*)d_in[1];
    const float* Wq  = (const float*)d_in[2];
    const float* bq  = (const float*)d_in[3];
    const float* Wk  = (const float*)d_in[4];
    const float* bk  = (const float*)d_in[5];
    const float* Wv  = (const float*)d_in[6];
    const float* bv  = (const float*)d_in[7];
    const float* Wo1 = (const float*)d_in[8];
    const float* bo1 = (const float*)d_in[9];
    const float* Wo2 = (const float*)d_in[10];
    const float* bo2 = (const float*)d_in[11];

    ta_repack<<<dim3(16), dim3(256), 0, stream>>>(Wq, Wk, Wv, Wo1, Wo2);
    ta_mfma<<<dim3(N_, B_), dim3(256), 0, stream>>>(
        x, ste, bq, bk, bv, bo1, bo2, (float*)d_out);
}

// Round 4
// 229.422 us; speedup vs baseline: 1.1048x; 1.0214x over previous
//
#include <hip/hip_runtime.h>
#include <hip/hip_bf16.h>

// Round 11 == Round 10 resubmit (r10 bench died on container infra, no signal).
// r10 changes vs r9, numerics bitwise identical:
//  - LDS 29568 -> 26112B: sh_o/sh_tmp overlay the dead sh_h region (h is
//    consumed into registers before the B->C barrier; tmp tail overlaps dead
//    sh_q head). LDS cap 5 -> 6 blocks/CU.
//  - Phase C wave-uniform causal truncation: t = wave*8 + (lane>>3), hi=lane&7;
//    s-loop bound is wave-uniform (8/16/24, template-unrolled). Skipped terms
//    are exactly 0.0f in the reference (exp(-32767-mx) underflows), so outputs
//    are unchanged while 33% of QK/exp/PV work disappears.

typedef unsigned short u16;
typedef unsigned int u32;
typedef __attribute__((ext_vector_type(8))) short bf16x8;
typedef __attribute__((ext_vector_type(4))) float f32x4;

#define B_ 32
#define T_ 24
#define N_ 325
#define D_ 64

#define WQKV_OFF 0        // 3072 frags * 8 el = 24576 el
#define WO1_OFF  24576    // 512 frags  * 8 el = 4096 el
#define WO2_OFF  28672    // 512 frags  * 8 el = 4096 el
#define WS_ELS   32768

__device__ __align__(64) u16 g_ws[WS_ELS];

__device__ __forceinline__ u16 f2bf(float f) {
    u32 u = __float_as_uint(f);
    return (u16)((u + 0x7FFFu + ((u >> 16) & 1u)) >> 16);  // RNE
}
__device__ __forceinline__ u32 pack2(float a, float b) {
    return (u32)f2bf(a) | ((u32)f2bf(b) << 16);
}

// B-frag (16x16x32): lane l holds B[k = ks*32 + (l>>4)*8 + j][n = nt*16 + (l&15)]
__global__ void ta_repack(const float* __restrict__ Wq, const float* __restrict__ Wk,
                          const float* __restrict__ Wv, const float* __restrict__ Wo1,
                          const float* __restrict__ Wo2) {
    int f = blockIdx.x * 256 + threadIdx.x;   // 0..4095
    const float* src;
    u16* dst;
    if (f < 3072) {
        int nt = f >> 8, ks = (f >> 6) & 3, l = f & 63;
        int nn = nt * 16 + (l & 15);
        int kb = ks * 32 + ((l >> 4) & 3) * 8;
        const float* W = (nn < 64) ? Wq : (nn < 128 ? Wk : Wv);
        src = W + kb * 64 + (nn & 63);
        dst = g_ws + WQKV_OFF + f * 8;
    } else {
        int fo = f - 3072;
        int m = fo >> 9;
        int fi = fo & 511;
        int nt = fi >> 7, ks = (fi >> 6) & 1, l = fi & 63;
        int nn = nt * 16 + (l & 15);
        int kb = ks * 32 + ((l >> 4) & 3) * 8;
        src = (m ? Wo2 : Wo1) + kb * 64 + nn;
        dst = g_ws + (m ? WO2_OFF : WO1_OFF) + fi * 8;
    }
    #pragma unroll
    for (int j = 0; j < 8; ++j) dst[j] = f2bf(src[j * 64]);
}

// Phase C body: rows t (fixed per thread), head hi, s-loop bound S wave-uniform.
// For s in (t, S): masked to -32767 -> exp underflows to exactly 0.0f, so
// truncating at S (instead of 24) is bitwise identical.
template<int S>
__device__ __forceinline__ void attn_rows(const float* __restrict__ sh_q,
                                          const float* __restrict__ sh_k,
                                          const float* __restrict__ sh_v,
                                          u16* __restrict__ sh_o,
                                          int t, int hi) {
    const float* qp = sh_q + t * 68 + hi * 8;
    float qr[8];
    #pragma unroll
    for (int d = 0; d < 8; ++d) qr[d] = qp[d] * 0.35355339059327373f;
    float e[S], mx = -3.0e38f;
    #pragma unroll
    for (int s = 0; s < S; ++s) {
        const float* kp = sh_k + s * 68 + hi * 8;
        float4 ka = *(const float4*)kp;
        float4 kb2 = *(const float4*)(kp + 4);
        float dot = qr[0] * ka.x;
        dot = fmaf(qr[1], ka.y, dot);  dot = fmaf(qr[2], ka.z, dot);
        dot = fmaf(qr[3], ka.w, dot);  dot = fmaf(qr[4], kb2.x, dot);
        dot = fmaf(qr[5], kb2.y, dot); dot = fmaf(qr[6], kb2.z, dot);
        dot = fmaf(qr[7], kb2.w, dot);
        float lg = (s <= t) ? dot : -32767.0f;
        e[s] = lg;
        mx = fmaxf(mx, lg);
    }
    float sum = 0.f;
    #pragma unroll
    for (int s = 0; s < S; ++s) { float ee = __expf(e[s] - mx); e[s] = ee; sum += ee; }
    float inv = 1.0f / sum;
    float ov[8];
    #pragma unroll
    for (int d = 0; d < 8; ++d) ov[d] = 0.f;
    #pragma unroll
    for (int s = 0; s < S; ++s) {
        float p2 = e[s] * inv;
        const float* vp = sh_v + s * 68 + hi * 8;
        float4 va = *(const float4*)vp;
        float4 vb = *(const float4*)(vp + 4);
        ov[0] = fmaf(p2, va.x, ov[0]); ov[1] = fmaf(p2, va.y, ov[1]);
        ov[2] = fmaf(p2, va.z, ov[2]); ov[3] = fmaf(p2, va.w, ov[3]);
        ov[4] = fmaf(p2, vb.x, ov[4]); ov[5] = fmaf(p2, vb.y, ov[5]);
        ov[6] = fmaf(p2, vb.z, ov[6]); ov[7] = fmaf(p2, vb.w, ov[7]);
    }
    u16* op = sh_o + t * 72 + hi * 8;
    *(u32*)(op + 0) = pack2(ov[0], ov[1]);
    *(u32*)(op + 2) = pack2(ov[2], ov[3]);
    *(u32*)(op + 4) = pack2(ov[4], ov[5]);
    *(u32*)(op + 6) = pack2(ov[6], ov[7]);
}

// LDS layout, 26112B total (overlays; padding-row reads over-read by design):
//  [0,     3456)  sh_o   u16 [24][72]    (overlays sh_h; h dead after B-frag reg loads)
//  [3456,  6912)  sh_tmp u16 [24][72]    (overlays sh_h tail + sh_q head; both dead by D1)
//  [0,     6528)  sh_h   u16 [24][136]   (phases A/B only)
//  [6528, 13056)  sh_q   f32 [24][68]
//  [13056,19584)  sh_k   f32 [24][68]
//  [19584,26112)  sh_v   f32 [24][68]
#define SMEM_BYTES 26112

__global__ __launch_bounds__(256) void ta_mfma(
    const float* __restrict__ x,   const float* __restrict__ ste,
    const float* __restrict__ bq,  const float* __restrict__ bk,
    const float* __restrict__ bv,  const float* __restrict__ bo1,
    const float* __restrict__ bo2, float* __restrict__ out)
{
    __shared__ __align__(16) char smem[SMEM_BYTES];
    u16*   sh_o   = (u16*)smem;
    u16*   sh_tmp = (u16*)(smem + 3456);
    u16*   sh_h   = (u16*)smem;
    float* sh_q   = (float*)(smem + 6528);
    float* sh_k   = (float*)(smem + 13056);
    float* sh_v   = (float*)(smem + 19584);

    const int tid  = threadIdx.x;
    const int w    = tid >> 6;
    const int l    = tid & 63;
    const int l15  = l & 15;
    const int quad = l >> 4;
    const int n = blockIdx.x;
    const int b = blockIdx.y;

    const int col16 = w * 16 + l15;
    // bias loads issued early so they overlap the staging loop
    float bqv = bq[col16],  bkv = bk[col16],  bvv = bv[col16];
    float b1v = bo1[col16], b2v = bo2[col16];

    // ---------------- Phase A: stage h rows 0..23 (fp32 -> bf16) ----------------
    for (int i = tid; i < 384; i += 256) {
        int f = i * 8;
        int t = f >> 7, kk = f & 127;
        int gbase = ((b * T_ + t) * N_ + n) * D_;
        const float* src = (kk < 64) ? (x + gbase + kk) : (ste + gbase + kk - 64);
        float4 a = *(const float4*)src;
        float4 c = *(const float4*)(src + 4);
        uint4 o;
        o.x = pack2(a.x, a.y); o.y = pack2(a.z, a.w);
        o.z = pack2(c.x, c.y); o.w = pack2(c.z, c.w);
        *(uint4*)(sh_h + t * 136 + kk) = o;
    }
    __syncthreads();

    // ---------------- Phase B: qkv = relu(h @ Wqkv + b) via MFMA ----------------
    // A-frag rows 16+l15 (l15>=8) over-read past sh_h into sh_q (possibly racing
    // with this phase's q-stores; values garbage either way, rows discarded).
    bf16x8 af0_0 = *(const bf16x8*)(sh_h + l15 * 136 + 0  + quad * 8);
    bf16x8 af0_1 = *(const bf16x8*)(sh_h + l15 * 136 + 32 + quad * 8);
    bf16x8 af0_2 = *(const bf16x8*)(sh_h + l15 * 136 + 64 + quad * 8);
    bf16x8 af0_3 = *(const bf16x8*)(sh_h + l15 * 136 + 96 + quad * 8);
    bf16x8 af1_0 = *(const bf16x8*)(sh_h + (16 + l15) * 136 + 0  + quad * 8);
    bf16x8 af1_1 = *(const bf16x8*)(sh_h + (16 + l15) * 136 + 32 + quad * 8);
    bf16x8 af1_2 = *(const bf16x8*)(sh_h + (16 + l15) * 136 + 64 + quad * 8);
    bf16x8 af1_3 = *(const bf16x8*)(sh_h + (16 + l15) * 136 + 96 + quad * 8);

    // --- Q (nt = w) ---
    {
        const int nt = w;
        f32x4 c0 = {0.f,0.f,0.f,0.f}, c1 = {0.f,0.f,0.f,0.f};
        bf16x8 bf;
        bf = *(const bf16x8*)(g_ws + WQKV_OFF + ((nt*4 + 0)*64 + l)*8);
        c0 = __builtin_amdgcn_mfma_f32_16x16x32_bf16(af0_0, bf, c0, 0,0,0);
        c1 = __builtin_amdgcn_mfma_f32_16x16x32_bf16(af1_0, bf, c1, 0,0,0);
        bf = *(const bf16x8*)(g_ws + WQKV_OFF + ((nt*4 + 1)*64 + l)*8);
        c0 = __builtin_amdgcn_mfma_f32_16x16x32_bf16(af0_1, bf, c0, 0,0,0);
        c1 = __builtin_amdgcn_mfma_f32_16x16x32_bf16(af1_1, bf, c1, 0,0,0);
        bf = *(const bf16x8*)(g_ws + WQKV_OFF + ((nt*4 + 2)*64 + l)*8);
        c0 = __builtin_amdgcn_mfma_f32_16x16x32_bf16(af0_2, bf, c0, 0,0,0);
        c1 = __builtin_amdgcn_mfma_f32_16x16x32_bf16(af1_2, bf, c1, 0,0,0);
        bf = *(const bf16x8*)(g_ws + WQKV_OFF + ((nt*4 + 3)*64 + l)*8);
        c0 = __builtin_amdgcn_mfma_f32_16x16x32_bf16(af0_3, bf, c0, 0,0,0);
        c1 = __builtin_amdgcn_mfma_f32_16x16x32_bf16(af1_3, bf, c1, 0,0,0);
        #pragma unroll
        for (int r = 0; r < 4; ++r) {
            int row0 = quad * 4 + r;
            sh_q[row0 * 68 + col16] = fmaxf(c0[r] + bqv, 0.f);
        }
        if (quad < 2) {
            #pragma unroll
            for (int r = 0; r < 4; ++r) {
                int row1 = 16 + quad * 4 + r;   // 16..23
                sh_q[row1 * 68 + col16] = fmaxf(c1[r] + bqv, 0.f);
            }
        }
    }
    // --- K (nt = w + 4) ---
    {
        const int nt = w + 4;
        f32x4 c0 = {0.f,0.f,0.f,0.f}, c1 = {0.f,0.f,0.f,0.f};
        bf16x8 bf;
        bf = *(const bf16x8*)(g_ws + WQKV_OFF + ((nt*4 + 0)*64 + l)*8);
        c0 = __builtin_amdgcn_mfma_f32_16x16x32_bf16(af0_0, bf, c0, 0,0,0);
        c1 = __builtin_amdgcn_mfma_f32_16x16x32_bf16(af1_0, bf, c1, 0,0,0);
        bf = *(const bf16x8*)(g_ws + WQKV_OFF + ((nt*4 + 1)*64 + l)*8);
        c0 = __builtin_amdgcn_mfma_f32_16x16x32_bf16(af0_1, bf, c0, 0,0,0);
        c1 = __builtin_amdgcn_mfma_f32_16x16x32_bf16(af1_1, bf, c1, 0,0,0);
        bf = *(const bf16x8*)(g_ws + WQKV_OFF + ((nt*4 + 2)*64 + l)*8);
        c0 = __builtin_amdgcn_mfma_f32_16x16x32_bf16(af0_2, bf, c0, 0,0,0);
        c1 = __builtin_amdgcn_mfma_f32_16x16x32_bf16(af1_2, bf, c1, 0,0,0);
        bf = *(const bf16x8*)(g_ws + WQKV_OFF + ((nt*4 + 3)*64 + l)*8);
        c0 = __builtin_amdgcn_mfma_f32_16x16x32_bf16(af0_3, bf, c0, 0,0,0);
        c1 = __builtin_amdgcn_mfma_f32_16x16x32_bf16(af1_3, bf, c1, 0,0,0);
        #pragma unroll
        for (int r = 0; r < 4; ++r) {
            int row0 = quad * 4 + r;
            sh_k[row0 * 68 + col16] = fmaxf(c0[r] + bkv, 0.f);
        }
        if (quad < 2) {
            #pragma unroll
            for (int r = 0; r < 4; ++r) {
                int row1 = 16 + quad * 4 + r;
                sh_k[row1 * 68 + col16] = fmaxf(c1[r] + bkv, 0.f);
            }
        }
    }
    // --- V (nt = w + 8) ---
    {
        const int nt = w + 8;
        f32x4 c0 = {0.f,0.f,0.f,0.f}, c1 = {0.f,0.f,0.f,0.f};
        bf16x8 bf;
        bf = *(const bf16x8*)(g_ws + WQKV_OFF + ((nt*4 + 0)*64 + l)*8);
        c0 = __builtin_amdgcn_mfma_f32_16x16x32_bf16(af0_0, bf, c0, 0,0,0);
        c1 = __builtin_amdgcn_mfma_f32_16x16x32_bf16(af1_0, bf, c1, 0,0,0);
        bf = *(const bf16x8*)(g_ws + WQKV_OFF + ((nt*4 + 1)*64 + l)*8);
        c0 = __builtin_amdgcn_mfma_f32_16x16x32_bf16(af0_1, bf, c0, 0,0,0);
        c1 = __builtin_amdgcn_mfma_f32_16x16x32_bf16(af1_1, bf, c1, 0,0,0);
        bf = *(const bf16x8*)(g_ws + WQKV_OFF + ((nt*4 + 2)*64 + l)*8);
        c0 = __builtin_amdgcn_mfma_f32_16x16x32_bf16(af0_2, bf, c0, 0,0,0);
        c1 = __builtin_amdgcn_mfma_f32_16x16x32_bf16(af1_2, bf, c1, 0,0,0);
        bf = *(const bf16x8*)(g_ws + WQKV_OFF + ((nt*4 + 3)*64 + l)*8);
        c0 = __builtin_amdgcn_mfma_f32_16x16x32_bf16(af0_3, bf, c0, 0,0,0);
        c1 = __builtin_amdgcn_mfma_f32_16x16x32_bf16(af1_3, bf, c1, 0,0,0);
        #pragma unroll
        for (int r = 0; r < 4; ++r) {
            int row0 = quad * 4 + r;
            sh_v[row0 * 68 + col16] = fmaxf(c0[r] + bvv, 0.f);
        }
        if (quad < 2) {
            #pragma unroll
            for (int r = 0; r < 4; ++r) {
                int row1 = 16 + quad * 4 + r;
                sh_v[row1 * 68 + col16] = fmaxf(c1[r] + bvv, 0.f);
            }
        }
    }
    __syncthreads();

    // ---------------- Phase C: attention (VALU), wave-uniform causal bound ----------------
    // waves 0..2: t = wave*8 + (lane>>3), hi = lane&7; s-loop 8/16/24. wave 3 idle.
    if (tid < 192) {
        const int w3 = tid >> 6;
        const int t  = w3 * 8 + ((tid & 63) >> 3);
        const int hi = tid & 7;
        if (w3 == 0)      attn_rows<8 >(sh_q, sh_k, sh_v, sh_o, t, hi);
        else if (w3 == 1) attn_rows<16>(sh_q, sh_k, sh_v, sh_o, t, hi);
        else              attn_rows<24>(sh_q, sh_k, sh_v, sh_o, t, hi);
    }
    __syncthreads();

    // ---------------- Phase D1: tmp = relu(o @ Wo1 + bo1) ----------------
    bf16x8 w1f0 = *(const bf16x8*)(g_ws + WO1_OFF + ((w*2 + 0)*64 + l)*8);
    bf16x8 w1f1 = *(const bf16x8*)(g_ws + WO1_OFF + ((w*2 + 1)*64 + l)*8);
    bf16x8 w2f0 = *(const bf16x8*)(g_ws + WO2_OFF + ((w*2 + 0)*64 + l)*8);
    bf16x8 w2f1 = *(const bf16x8*)(g_ws + WO2_OFF + ((w*2 + 1)*64 + l)*8);
    // a10/a11 rows 24..31 over-read past sh_o into stale sh_tmp; rows discarded.
    {
        bf16x8 a00 = *(const bf16x8*)(sh_o + l15 * 72 + 0  + quad * 8);
        bf16x8 a01 = *(const bf16x8*)(sh_o + l15 * 72 + 32 + quad * 8);
        bf16x8 a10 = *(const bf16x8*)(sh_o + (16 + l15) * 72 + 0  + quad * 8);
        bf16x8 a11 = *(const bf16x8*)(sh_o + (16 + l15) * 72 + 32 + quad * 8);
        f32x4 c0 = {0.f,0.f,0.f,0.f}, c1 = {0.f,0.f,0.f,0.f};
        c0 = __builtin_amdgcn_mfma_f32_16x16x32_bf16(a00, w1f0, c0, 0,0,0);
        c1 = __builtin_amdgcn_mfma_f32_16x16x32_bf16(a10, w1f0, c1, 0,0,0);
        c0 = __builtin_amdgcn_mfma_f32_16x16x32_bf16(a01, w1f1, c0, 0,0,0);
        c1 = __builtin_amdgcn_mfma_f32_16x16x32_bf16(a11, w1f1, c1, 0,0,0);
        __syncthreads();   // all sh_o reads retired before tmp overwrites below
        #pragma unroll
        for (int r = 0; r < 4; ++r) {
            int row0 = quad * 4 + r;
            sh_tmp[row0 * 72 + col16] = f2bf(fmaxf(c0[r] + b1v, 0.f));
        }
        if (quad < 2) {
            #pragma unroll
            for (int r = 0; r < 4; ++r) {
                int row1 = 16 + quad * 4 + r;
                sh_tmp[row1 * 72 + col16] = f2bf(fmaxf(c1[r] + b1v, 0.f));
            }
        }
    }
    __syncthreads();

    // ---------------- Phase D2: out = tmp @ Wo2 + bo2 -> global (fp32) ----------------
    // tmp rows 24..31 over-read into dead sh_q region; rows discarded.
    {
        bf16x8 a00 = *(const bf16x8*)(sh_tmp + l15 * 72 + 0  + quad * 8);
        bf16x8 a01 = *(const bf16x8*)(sh_tmp + l15 * 72 + 32 + quad * 8);
        bf16x8 a10 = *(const bf16x8*)(sh_tmp + (16 + l15) * 72 + 0  + quad * 8);
        bf16x8 a11 = *(const bf16x8*)(sh_tmp + (16 + l15) * 72 + 32 + quad * 8);
        f32x4 c0 = {0.f,0.f,0.f,0.f}, c1 = {0.f,0.f,0.f,0.f};
        c0 = __builtin_amdgcn_mfma_f32_16x16x32_bf16(a00, w2f0, c0, 0,0,0);
        c1 = __builtin_amdgcn_mfma_f32_16x16x32_bf16(a10, w2f0, c1, 0,0,0);
        c0 = __builtin_amdgcn_mfma_f32_16x16x32_bf16(a01, w2f1, c0, 0,0,0);
        c1 = __builtin_amdgcn_mfma_f32_16x16x32_bf16(a11, w2f1, c1, 0,0,0);
        #pragma unroll
        for (int r = 0; r < 4; ++r) {
            int row0 = quad * 4 + r;
            out[((b * T_ + row0) * N_ + n) * D_ + col16] = c0[r] + b2v;
            int row1 = 16 + row0;
            if (row1 < T_)
                out[((b * T_ + row1) * N_ + n) * D_ + col16] = c1[r] + b2v;
        }
    }
}

extern "C" void kernel_launch(void* const* d_in, const int* in_sizes, int n_in,
                              void* d_out, int out_size, void* d_ws, size_t ws_size,
                              hipStream_t stream) {
    (void)in_sizes; (void)n_in; (void)out_size; (void)d_ws; (void)ws_size;
    const float* x   = (const float*)d_in[0];
    const float* ste = (const float*)d_in[1];
    const float* Wq  = (const float*)d_in[2];
    const float* bq  = (const float*)d_in[3];
    const float* Wk  = (const float*)d_in[4];
    const float* bk  = (const float*)d_in[5];
    const float* Wv  = (const float*)d_in[6];
    const float* bv  = (const float*)d_in[7];
    const float* Wo1 = (const float*)d_in[8];
    const float* bo1 = (const float*)d_in[9];
    const float* Wo2 = (const float*)d_in[10];
    const float* bo2 = (const float*)d_in[11];

    ta_repack<<<dim3(16), dim3(256), 0, stream>>>(Wq, Wk, Wv, Wo1, Wo2);
    ta_mfma<<<dim3(N_, B_), dim3(256), 0, stream>>>(
        x, ste, bq, bk, bv, bo1, bo2, (float*)d_out);
}